// Round 8
// baseline (333.008 us; speedup 1.0000x reference)
//
#include <hip/hip_runtime.h>

#define NN 100000
#define NE 1600000
#define NB ((NN + 255) / 256)

typedef unsigned int uint32;
typedef unsigned short ushort16;
typedef float f32x4 __attribute__((ext_vector_type(4)));
typedef short bf16x8 __attribute__((ext_vector_type(8)));

__device__ __forceinline__ float bflo(uint32 u) { return __uint_as_float(u << 16); }
__device__ __forceinline__ float bfhi(uint32 u) { return __uint_as_float(u & 0xffff0000u); }
__device__ __forceinline__ uint32 bfbits(float v) { return (__float_as_uint(v) + 0x8000u) >> 16; }
__device__ __forceinline__ uint32 pack2(float a, float b) { return bfbits(a) | (bfbits(b) << 16); }

// channel permutation: sigma(c) swaps cc (bits 5:4) and qq (bits 3:2) fields
__device__ __forceinline__ int sigma_ch(int c) {
    return (((c >> 2) & 3) << 4) + (((c >> 4) & 3) << 2) + (c & 3);
}

// ---------------- CSR build ----------------
// single atomic pass: deg counts + per-edge rank
__global__ __launch_bounds__(256) void k_hist_rank(const int* __restrict__ ei, int* __restrict__ deg,
                                                   int* __restrict__ rank, int E) {
    int e = blockIdx.x * 256 + threadIdx.x;
    if (e < E) rank[e] = atomicAdd(&deg[ei[e]], 1);
}

__global__ __launch_bounds__(256) void k_hist(const int* __restrict__ ei, int* __restrict__ deg, int E) {
    int e = blockIdx.x * 256 + threadIdx.x;
    if (e < E) atomicAdd(&deg[ei[e]], 1);
}

__global__ __launch_bounds__(256) void k_scan1(const int* __restrict__ deg, int* __restrict__ offs,
                                               int* __restrict__ bsums, int n) {
    __shared__ int s[256];
    int tid = threadIdx.x;
    int i = blockIdx.x * 256 + tid;
    int v = (i < n) ? deg[i] : 0;
    int acc = v;
    s[tid] = acc;
    __syncthreads();
    #pragma unroll
    for (int off = 1; off < 256; off <<= 1) {
        int t = (tid >= off) ? s[tid - off] : 0;
        __syncthreads();
        acc += t;
        s[tid] = acc;
        __syncthreads();
    }
    if (i < n) offs[i] = acc - v;
    if (tid == 255) bsums[blockIdx.x] = acc;
}

__global__ __launch_bounds__(512) void k_scan2(int* __restrict__ bsums, int nb) {
    __shared__ int s[512];
    int tid = threadIdx.x;
    int v = (tid < nb) ? bsums[tid] : 0;
    int acc = v;
    s[tid] = acc;
    __syncthreads();
    #pragma unroll
    for (int off = 1; off < 512; off <<= 1) {
        int t = (tid >= off) ? s[tid - off] : 0;
        __syncthreads();
        acc += t;
        s[tid] = acc;
        __syncthreads();
    }
    bsums[tid] = acc - v;
}

// finalize offs in place (global exclusive prefix)
__global__ __launch_bounds__(256) void k_offs(int* __restrict__ offs, const int* __restrict__ bsums, int n) {
    int i = blockIdx.x * 256 + threadIdx.x;
    if (i < n) offs[i] += bsums[i >> 8];
}

// sorted[offs[row] + rank[e]] = e
__global__ __launch_bounds__(256) void k_sorted(const int* __restrict__ ei, const int* __restrict__ offs,
                                                const int* __restrict__ rank, int* __restrict__ sorted, int E) {
    int e = blockIdx.x * 256 + threadIdx.x;
    if (e >= E) return;
    sorted[offs[ei[e]] + rank[e]] = e;
}

// ---------------- Wc = W1b @ W2a[32:96] (rows sigma-permuted when perm=1), bc = b1b @ W2a[32:96] ----------------
__global__ __launch_bounds__(256) void k_prep(const float* __restrict__ W1b, const float* __restrict__ b1b,
                                              const float* __restrict__ W2a,
                                              float* __restrict__ Wc, float* __restrict__ bc, int perm) {
    int t = blockIdx.x * 256 + threadIdx.x;  // 0..4095
    int r = t >> 6, c = t & 63;
    float a = 0.f;
    for (int k = 0; k < 64; ++k) a += W1b[r * 64 + k] * W2a[(32 + k) * 64 + c];
    int rs = perm ? sigma_ch(r) : r;
    Wc[rs * 64 + c] = a;
    if (t < 64) {
        float bacc = 0.f;
        for (int k = 0; k < 64; ++k) bacc += b1b[k] * W2a[(32 + k) * 64 + t];
        bc[t] = bacc;
    }
}

// ---------------- fused edge MLP + segment sum: one wave per node ----------------
// Per 16-edge tile: 8x mfma_f32_16x16x32_bf16.
//   A = W1a^T fragments (channels on M; lane supplies row en per cc-block), from LDS.
//   B = gathered ea[e] rows (ea-part) / x[col] rows (x-part); edge on column en.
//   C init = b1a per channel (zero for invalid tail lanes).
// D/C layout: lane(qq,en) -> col=en, rows qq*4+r of cc-block => channel cc*16+qq*4+r.
// After relu+per-lane accumulate: butterfly allreduce over en; lanes en==0 write
// Sacc[node][qq*16+cc*4+r] (sigma positions, matching Wc's permuted rows).
__global__ __launch_bounds__(256) void k_edge_fused(
    const int* __restrict__ ei, const float* __restrict__ ea, const float* __restrict__ x,
    const float* __restrict__ W1a, const float* __restrict__ b1a,
    const int* __restrict__ deg, const int* __restrict__ offs, const int* __restrict__ sorted,
    float* __restrict__ Sacc)
{
    __shared__ ushort16 sWtB[64 * 40];  // W1a rows 32..63 (ea part), [ch][k], padded row 40
    __shared__ ushort16 sWtA[64 * 40];  // W1a rows 0..31  (x part),  [ch][k]
    for (int idx = threadIdx.x; idx < 2048; idx += 256) {
        int ch = idx & 63, k = idx >> 6;
        sWtB[ch * 40 + k] = (ushort16)bfbits(W1a[(32 + k) * 64 + ch]);
        sWtA[ch * 40 + k] = (ushort16)bfbits(W1a[k * 64 + ch]);
    }
    __syncthreads();

    int lane = threadIdx.x & 63;
    int wave = threadIdx.x >> 6;
    int en = lane & 15;
    int qq = lane >> 4;
    int node = blockIdx.x * 4 + wave;
    if (node >= NN) return;

    bf16x8 wB[4], wA[4];
    #pragma unroll
    for (int cc = 0; cc < 4; ++cc) {
        wB[cc] = *(const bf16x8*)&sWtB[(cc * 16 + en) * 40 + qq * 8];
        wA[cc] = *(const bf16x8*)&sWtA[(cc * 16 + en) * 40 + qq * 8];
    }
    // bias C-init per channel: binit[cc][r] = b1a[cc*16 + qq*4 + r]
    f32x4 binit[4];
    #pragma unroll
    for (int cc = 0; cc < 4; ++cc) {
        float4 b = *(const float4*)(b1a + cc * 16 + qq * 4);
        binit[cc] = (f32x4){b.x, b.y, b.z, b.w};
    }

    int d = deg[node];
    int start = offs[node];

    f32x4 tot[4];
    #pragma unroll
    for (int cc = 0; cc < 4; ++cc) tot[cc] = (f32x4){0.f, 0.f, 0.f, 0.f};

    #pragma unroll 1
    for (int t0 = 0; t0 < d; t0 += 16) {
        int sidx = t0 + en;
        bool ok = sidx < d;
        union { uint4 u; bf16x8 v; } bea, bx;
        f32x4 acc[4];
        if (ok) {
            int e = sorted[start + sidx];
            int col = ei[NE + e];
            const float* ar = ea + (size_t)e * 32 + qq * 8;
            float4 a0 = *(const float4*)ar;
            float4 a1 = *(const float4*)(ar + 4);
            bea.u.x = pack2(a0.x, a0.y); bea.u.y = pack2(a0.z, a0.w);
            bea.u.z = pack2(a1.x, a1.y); bea.u.w = pack2(a1.z, a1.w);
            const float* xr = x + (size_t)col * 32 + qq * 8;
            float4 x0 = *(const float4*)xr;
            float4 x1 = *(const float4*)(xr + 4);
            bx.u.x = pack2(x0.x, x0.y); bx.u.y = pack2(x0.z, x0.w);
            bx.u.z = pack2(x1.x, x1.y); bx.u.w = pack2(x1.z, x1.w);
            #pragma unroll
            for (int cc = 0; cc < 4; ++cc) acc[cc] = binit[cc];
        } else {
            bea.u = make_uint4(0, 0, 0, 0);
            bx.u = make_uint4(0, 0, 0, 0);
            #pragma unroll
            for (int cc = 0; cc < 4; ++cc) acc[cc] = (f32x4){0.f, 0.f, 0.f, 0.f};
        }
        #pragma unroll
        for (int cc = 0; cc < 4; ++cc)
            acc[cc] = __builtin_amdgcn_mfma_f32_16x16x32_bf16(wB[cc], bea.v, acc[cc], 0, 0, 0);
        #pragma unroll
        for (int cc = 0; cc < 4; ++cc)
            acc[cc] = __builtin_amdgcn_mfma_f32_16x16x32_bf16(wA[cc], bx.v, acc[cc], 0, 0, 0);
        #pragma unroll
        for (int cc = 0; cc < 4; ++cc) {
            #pragma unroll
            for (int r = 0; r < 4; ++r)
                tot[cc][r] += fmaxf(acc[cc][r], 0.f);
        }
    }

    // butterfly allreduce over the 16 en-lanes (masks 1,2,4,8 stay inside qq group)
    #pragma unroll
    for (int m = 1; m < 16; m <<= 1) {
        #pragma unroll
        for (int cc = 0; cc < 4; ++cc) {
            #pragma unroll
            for (int r = 0; r < 4; ++r)
                tot[cc][r] += __shfl_xor(tot[cc][r], m);
        }
    }
    if (en == 0) {
        float* sp = Sacc + (size_t)node * 64 + qq * 16;
        #pragma unroll
        for (int cc = 0; cc < 4; ++cc)
            *(float4*)(sp + cc * 4) = make_float4(tot[cc][0], tot[cc][1], tot[cc][2], tot[cc][3]);
    }
}

// ---------------- fallback: per-edge atomic scatter (natural channel order) ----------------
__global__ __launch_bounds__(256) void k_edge_atom(
    const float* __restrict__ x, const int* __restrict__ ei, const float* __restrict__ ea,
    const float* __restrict__ W1a, const float* __restrict__ b1a,
    float* __restrict__ Sacc, int E)
{
    __shared__ float sWB[32 * 64];
    __shared__ float sWA[32 * 64];
    __shared__ float sb[64];
    for (int t = threadIdx.x; t < 32 * 64; t += 256) {
        sWB[t] = W1a[32 * 64 + t];
        sWA[t] = W1a[t];
    }
    if (threadIdx.x < 64) sb[threadIdx.x] = b1a[threadIdx.x];
    __syncthreads();
    int e = blockIdx.x * 256 + threadIdx.x;
    if (e >= E) return;
    int row = ei[e];
    int col = ei[NE + e];
    float h[64];
    #pragma unroll
    for (int j = 0; j < 64; ++j) h[j] = sb[j];
    const float4* xrow = (const float4*)(x + (size_t)col * 32);
    #pragma unroll
    for (int k4 = 0; k4 < 8; ++k4) {
        float4 v = xrow[k4];
        float vv[4] = {v.x, v.y, v.z, v.w};
        #pragma unroll
        for (int c = 0; c < 4; ++c) {
            float val = vv[c];
            const float4* wr = (const float4*)&sWA[(k4 * 4 + c) * 64];
            #pragma unroll
            for (int j4 = 0; j4 < 16; ++j4) {
                float4 w = wr[j4];
                h[j4 * 4 + 0] += val * w.x; h[j4 * 4 + 1] += val * w.y;
                h[j4 * 4 + 2] += val * w.z; h[j4 * 4 + 3] += val * w.w;
            }
        }
    }
    const float4* earow = (const float4*)(ea + (size_t)e * 32);
    #pragma unroll
    for (int k4 = 0; k4 < 8; ++k4) {
        float4 v = earow[k4];
        float vv[4] = {v.x, v.y, v.z, v.w};
        #pragma unroll
        for (int c = 0; c < 4; ++c) {
            float val = vv[c];
            const float4* wr = (const float4*)&sWB[(k4 * 4 + c) * 64];
            #pragma unroll
            for (int j4 = 0; j4 < 16; ++j4) {
                float4 w = wr[j4];
                h[j4 * 4 + 0] += val * w.x; h[j4 * 4 + 1] += val * w.y;
                h[j4 * 4 + 2] += val * w.z; h[j4 * 4 + 3] += val * w.w;
            }
        }
    }
    float* srow = Sacc + (size_t)row * 64;
    #pragma unroll
    for (int j = 0; j < 64; ++j) atomicAdd(&srow[j], fmaxf(h[j], 0.f));
}

// ---------------- node MLP: out = relu(x@W2a_top + (Sacc/d)@Wc + bc + b2a) @ W2b + b2b ----------------
__global__ __launch_bounds__(256) void k_node(
    const float* __restrict__ x, const float* __restrict__ Sacc, const int* __restrict__ deg,
    const float* __restrict__ Wc, const float* __restrict__ bc,
    const float* __restrict__ W2a, const float* __restrict__ b2a,
    const float* __restrict__ W2b, const float* __restrict__ b2b,
    float* __restrict__ out, int N)
{
    __shared__ float sWc[64 * 64];
    __shared__ float sW2ax[32 * 64];
    __shared__ float sW2b[64 * 32];
    __shared__ float sbc2[64];
    __shared__ float sb2[64];
    __shared__ float sb2b_[32];
    for (int t = threadIdx.x; t < 64 * 64; t += 256) sWc[t] = Wc[t];
    for (int t = threadIdx.x; t < 32 * 64; t += 256) sW2ax[t] = W2a[t];
    for (int t = threadIdx.x; t < 64 * 32; t += 256) sW2b[t] = W2b[t];
    if (threadIdx.x < 64) {
        sbc2[threadIdx.x] = bc[threadIdx.x] + b2a[threadIdx.x];
        sb2[threadIdx.x] = b2a[threadIdx.x];
    }
    if (threadIdx.x < 32) sb2b_[threadIdx.x] = b2b[threadIdx.x];
    __syncthreads();

    int i = blockIdx.x * 256 + threadIdx.x;
    if (i >= N) return;
    int d = deg[i];
    float inv = (d > 0) ? 1.f / (float)d : 0.f;

    float h2[64];
    #pragma unroll
    for (int j = 0; j < 64; ++j) h2[j] = (d > 0) ? sbc2[j] : sb2[j];

    const float4* sp = (const float4*)(Sacc + (size_t)i * 64);
    #pragma unroll 2
    for (int k4 = 0; k4 < 16; ++k4) {
        float4 v = sp[k4];
        float vv[4] = {v.x * inv, v.y * inv, v.z * inv, v.w * inv};
        #pragma unroll
        for (int c = 0; c < 4; ++c) {
            float val = vv[c];
            const float4* wr = (const float4*)&sWc[(k4 * 4 + c) * 64];
            #pragma unroll
            for (int j4 = 0; j4 < 16; ++j4) {
                float4 w = wr[j4];
                h2[j4 * 4 + 0] += val * w.x; h2[j4 * 4 + 1] += val * w.y;
                h2[j4 * 4 + 2] += val * w.z; h2[j4 * 4 + 3] += val * w.w;
            }
        }
    }
    const float4* xrow = (const float4*)(x + (size_t)i * 32);
    #pragma unroll 2
    for (int k4 = 0; k4 < 8; ++k4) {
        float4 v = xrow[k4];
        float vv[4] = {v.x, v.y, v.z, v.w};
        #pragma unroll
        for (int c = 0; c < 4; ++c) {
            float val = vv[c];
            const float4* wr = (const float4*)&sW2ax[(k4 * 4 + c) * 64];
            #pragma unroll
            for (int j4 = 0; j4 < 16; ++j4) {
                float4 w = wr[j4];
                h2[j4 * 4 + 0] += val * w.x; h2[j4 * 4 + 1] += val * w.y;
                h2[j4 * 4 + 2] += val * w.z; h2[j4 * 4 + 3] += val * w.w;
            }
        }
    }
    #pragma unroll
    for (int j = 0; j < 64; ++j) h2[j] = fmaxf(h2[j], 0.f);

    float o[32];
    #pragma unroll
    for (int j = 0; j < 32; ++j) o[j] = sb2b_[j];
    #pragma unroll
    for (int k = 0; k < 64; ++k) {
        float val = h2[k];
        const float4* wr = (const float4*)&sW2b[k * 32];
        #pragma unroll
        for (int j4 = 0; j4 < 8; ++j4) {
            float4 w = wr[j4];
            o[j4 * 4 + 0] += val * w.x; o[j4 * 4 + 1] += val * w.y;
            o[j4 * 4 + 2] += val * w.z; o[j4 * 4 + 3] += val * w.w;
        }
    }
    float4* orow = (float4*)(out + (size_t)i * 32);
    #pragma unroll
    for (int q = 0; q < 8; ++q)
        orow[q] = make_float4(o[q * 4], o[q * 4 + 1], o[q * 4 + 2], o[q * 4 + 3]);
}

extern "C" void kernel_launch(void* const* d_in, const int* in_sizes, int n_in,
                              void* d_out, int out_size, void* d_ws, size_t ws_size,
                              hipStream_t stream) {
    const float* x   = (const float*)d_in[0];
    const int*   ei  = (const int*)d_in[1];
    const float* ea  = (const float*)d_in[2];
    const float* W1a = (const float*)d_in[5];
    const float* b1a = (const float*)d_in[6];
    const float* W1b = (const float*)d_in[7];
    const float* b1b = (const float*)d_in[8];
    const float* W2a = (const float*)d_in[9];
    const float* b2a = (const float*)d_in[10];
    const float* W2b = (const float*)d_in[11];
    const float* b2b = (const float*)d_in[12];
    float* out = (float*)d_out;

    // workspace layout (~40 MB)
    char* p = (char*)d_ws;
    int* deg        = (int*)p;        p += (size_t)NN * 4;
    int* offs       = (int*)p;        p += (size_t)NN * 4;
    int* bsums      = (int*)p;        p += 2048;
    float* Wc       = (float*)p;      p += 4096 * 4;
    float* bc       = (float*)p;      p += 64 * 4;
    int* rank       = (int*)p;        p += (size_t)NE * 4;
    int* sorted     = (int*)p;        p += (size_t)NE * 4;
    float* Sacc     = (float*)p;      p += (size_t)NN * 64 * 4;
    size_t need     = (size_t)(p - (char*)d_ws);

    dim3 blk(256);
    bool primary = (ws_size >= need);

    if (primary) {
        hipMemsetAsync(deg, 0, (size_t)NN * 4, stream);
        hipLaunchKernelGGL(k_hist_rank, dim3((NE + 255) / 256), blk, 0, stream, ei, deg, rank, NE);
        hipLaunchKernelGGL(k_scan1, dim3(NB), blk, 0, stream, deg, offs, bsums, NN);
        hipLaunchKernelGGL(k_scan2, dim3(1), dim3(512), 0, stream, bsums, NB);
        hipLaunchKernelGGL(k_offs, dim3(NB), blk, 0, stream, offs, bsums, NN);
        hipLaunchKernelGGL(k_sorted, dim3((NE + 255) / 256), blk, 0, stream, ei, offs, rank, sorted, NE);
        hipLaunchKernelGGL(k_prep, dim3(16), blk, 0, stream, W1b, b1b, W2a, Wc, bc, 1);
        hipLaunchKernelGGL(k_edge_fused, dim3((NN + 3) / 4), blk, 0, stream,
                           ei, ea, x, W1a, b1a, deg, offs, sorted, Sacc);
        hipLaunchKernelGGL(k_node, dim3(NB), blk, 0, stream,
                           x, Sacc, deg, Wc, bc, W2a, b2a, W2b, b2b, out, NN);
    } else {
        // fallback: fp32 atomic scatter (natural channel order)
        hipMemsetAsync(deg, 0, (size_t)NN * 4, stream);
        hipMemsetAsync(Sacc, 0, (size_t)NN * 64 * 4, stream);
        hipLaunchKernelGGL(k_hist, dim3((NE + 255) / 256), blk, 0, stream, ei, deg, NE);
        hipLaunchKernelGGL(k_prep, dim3(16), blk, 0, stream, W1b, b1b, W2a, Wc, bc, 0);
        hipLaunchKernelGGL(k_edge_atom, dim3((NE + 255) / 256), blk, 0, stream,
                           x, ei, ea, W1a, b1a, Sacc, NE);
        hipLaunchKernelGGL(k_node, dim3(NB), blk, 0, stream,
                           x, Sacc, deg, Wc, bc, W2a, b2a, W2b, b2b, out, NN);
    }
}

// Round 9
// 313.446 us; speedup vs baseline: 1.0624x; 1.0624x over previous
//
#include <hip/hip_runtime.h>

#define NN 100000
#define NE 1600000
#define NB ((NN + 255) / 256)

typedef unsigned int uint32;
typedef unsigned short ushort16;
typedef float f32x4 __attribute__((ext_vector_type(4)));
typedef short bf16x8 __attribute__((ext_vector_type(8)));

__device__ __forceinline__ float bflo(uint32 u) { return __uint_as_float(u << 16); }
__device__ __forceinline__ float bfhi(uint32 u) { return __uint_as_float(u & 0xffff0000u); }
__device__ __forceinline__ uint32 bfbits(float v) { return (__float_as_uint(v) + 0x8000u) >> 16; }
__device__ __forceinline__ uint32 pack2(float a, float b) { return bfbits(a) | (bfbits(b) << 16); }

// channel permutation: sigma(c) swaps cc (bits 5:4) and qq (bits 3:2) fields
__device__ __forceinline__ int sigma_ch(int c) {
    return (((c >> 2) & 3) << 4) + (((c >> 4) & 3) << 2) + (c & 3);
}

// ---------------- CSR build ----------------
__global__ __launch_bounds__(256) void k_hist_rank(const int* __restrict__ ei, int* __restrict__ deg,
                                                   int* __restrict__ rank, int E) {
    int e = blockIdx.x * 256 + threadIdx.x;
    if (e < E) rank[e] = atomicAdd(&deg[ei[e]], 1);
}

__global__ __launch_bounds__(256) void k_hist(const int* __restrict__ ei, int* __restrict__ deg, int E) {
    int e = blockIdx.x * 256 + threadIdx.x;
    if (e < E) atomicAdd(&deg[ei[e]], 1);
}

__global__ __launch_bounds__(256) void k_scan1(const int* __restrict__ deg, int* __restrict__ offs,
                                               int* __restrict__ bsums, int n) {
    __shared__ int s[256];
    int tid = threadIdx.x;
    int i = blockIdx.x * 256 + tid;
    int v = (i < n) ? deg[i] : 0;
    int acc = v;
    s[tid] = acc;
    __syncthreads();
    #pragma unroll
    for (int off = 1; off < 256; off <<= 1) {
        int t = (tid >= off) ? s[tid - off] : 0;
        __syncthreads();
        acc += t;
        s[tid] = acc;
        __syncthreads();
    }
    if (i < n) offs[i] = acc - v;
    if (tid == 255) bsums[blockIdx.x] = acc;
}

__global__ __launch_bounds__(512) void k_scan2(int* __restrict__ bsums, int nb) {
    __shared__ int s[512];
    int tid = threadIdx.x;
    int v = (tid < nb) ? bsums[tid] : 0;
    int acc = v;
    s[tid] = acc;
    __syncthreads();
    #pragma unroll
    for (int off = 1; off < 512; off <<= 1) {
        int t = (tid >= off) ? s[tid - off] : 0;
        __syncthreads();
        acc += t;
        s[tid] = acc;
        __syncthreads();
    }
    bsums[tid] = acc - v;
}

__global__ __launch_bounds__(256) void k_offs(int* __restrict__ offs, const int* __restrict__ bsums, int n) {
    int i = blockIdx.x * 256 + threadIdx.x;
    if (i < n) offs[i] += bsums[i >> 8];
}

// ecol[offs[row] + rank[e]] = (e, col)
__global__ __launch_bounds__(256) void k_sorted(const int* __restrict__ ei, const int* __restrict__ offs,
                                                const int* __restrict__ rank, int2* __restrict__ ecol, int E) {
    int e = blockIdx.x * 256 + threadIdx.x;
    if (e >= E) return;
    int slot = offs[ei[e]] + rank[e];
    ecol[slot] = make_int2(e, ei[E + e]);
}

// ---------------- prep: Wc = W1b @ W2a[32:96] (rows sigma'd when perm), bc, wpack A-fragments ----------------
// wpack layout: [table(0=ea part rows 32..63, 1=x part rows 0..31)][cc 0..3][lane 0..63] -> uint4 (8 bf16)
// fragment element i for lane(qq,en): W1a[(table?0:32) + qq*8+i][cc*16+en]
__global__ __launch_bounds__(256) void k_prep(const float* __restrict__ W1b, const float* __restrict__ b1b,
                                              const float* __restrict__ W2a, const float* __restrict__ W1a,
                                              float* __restrict__ Wc, float* __restrict__ bc,
                                              uint4* __restrict__ wpack, int perm) {
    int t = blockIdx.x * 256 + threadIdx.x;  // 0..4095
    int r = t >> 6, c = t & 63;
    float a = 0.f;
    for (int k = 0; k < 64; ++k) a += W1b[r * 64 + k] * W2a[(32 + k) * 64 + c];
    int rs = perm ? sigma_ch(r) : r;
    Wc[rs * 64 + c] = a;
    if (t < 64) {
        float bacc = 0.f;
        for (int k = 0; k < 64; ++k) bacc += b1b[k] * W2a[(32 + k) * 64 + t];
        bc[t] = bacc;
    }
    if (t < 512) {
        int table = t >> 8;
        int cc = (t >> 6) & 3;
        int lane = t & 63;
        int qq = lane >> 4, en = lane & 15;
        int ch = cc * 16 + en;
        uint32 w[4];
        #pragma unroll
        for (int j = 0; j < 4; ++j) {
            int k0 = qq * 8 + j * 2;
            int row0 = (table ? 0 : 32) + k0;
            w[j] = pack2(W1a[row0 * 64 + ch], W1a[(row0 + 1) * 64 + ch]);
        }
        wpack[t] = make_uint4(w[0], w[1], w[2], w[3]);
    }
}

// ---------------- fused edge MLP + segment sum: one wave per node, no LDS ----------------
// Per 16-edge tile: 8x mfma_f32_16x16x32_bf16.
//   A = wpack fragments (channels on M), B = gathered ea / x rows (edge on col), C init = b1a.
// D/C: lane(qq,en) -> col=en, channel cc*16+qq*4+r. After relu+accumulate: butterfly over en;
// en==0 lanes write Sacc[node][qq*16+cc*4+r] (sigma positions, matching Wc rows).
__global__ __launch_bounds__(256) void k_edge_fused(
    const float* __restrict__ ea, const float* __restrict__ x,
    const uint4* __restrict__ wpack, const float* __restrict__ b1a,
    const int* __restrict__ deg, const int* __restrict__ offs, const int2* __restrict__ ecol,
    float* __restrict__ Sacc)
{
    int lane = threadIdx.x & 63;
    int wave = threadIdx.x >> 6;
    int en = lane & 15;
    int qq = lane >> 4;
    int node = blockIdx.x * 4 + wave;
    if (node >= NN) return;

    union { uint4 u; bf16x8 v; } wB[4], wA[4];
    #pragma unroll
    for (int cc = 0; cc < 4; ++cc) {
        wB[cc].u = wpack[cc * 64 + lane];
        wA[cc].u = wpack[256 + cc * 64 + lane];
    }
    f32x4 binit[4];
    #pragma unroll
    for (int cc = 0; cc < 4; ++cc) {
        float4 b = *(const float4*)(b1a + cc * 16 + qq * 4);
        binit[cc] = (f32x4){b.x, b.y, b.z, b.w};
    }

    int d = deg[node];
    int start = offs[node];

    f32x4 tot[4];
    #pragma unroll
    for (int cc = 0; cc < 4; ++cc) tot[cc] = (f32x4){0.f, 0.f, 0.f, 0.f};

    #pragma unroll 1
    for (int t0 = 0; t0 < d; t0 += 16) {
        int sidx = t0 + en;
        bool ok = sidx < d;
        int slot = start + (ok ? sidx : d - 1);
        int2 ec = ecol[slot];

        const float* ar = ea + (size_t)ec.x * 32 + qq * 8;
        float4 a0 = *(const float4*)ar;
        float4 a1 = *(const float4*)(ar + 4);
        const float* xr = x + (size_t)ec.y * 32 + qq * 8;
        float4 x0 = *(const float4*)xr;
        float4 x1 = *(const float4*)(xr + 4);

        union { uint4 u; bf16x8 v; } bea, bx;
        f32x4 acc[4];
        if (ok) {
            bea.u.x = pack2(a0.x, a0.y); bea.u.y = pack2(a0.z, a0.w);
            bea.u.z = pack2(a1.x, a1.y); bea.u.w = pack2(a1.z, a1.w);
            bx.u.x = pack2(x0.x, x0.y); bx.u.y = pack2(x0.z, x0.w);
            bx.u.z = pack2(x1.x, x1.y); bx.u.w = pack2(x1.z, x1.w);
            #pragma unroll
            for (int cc = 0; cc < 4; ++cc) acc[cc] = binit[cc];
        } else {
            bea.u = make_uint4(0, 0, 0, 0);
            bx.u = make_uint4(0, 0, 0, 0);
            #pragma unroll
            for (int cc = 0; cc < 4; ++cc) acc[cc] = (f32x4){0.f, 0.f, 0.f, 0.f};
        }
        #pragma unroll
        for (int cc = 0; cc < 4; ++cc)
            acc[cc] = __builtin_amdgcn_mfma_f32_16x16x32_bf16(wB[cc].v, bea.v, acc[cc], 0, 0, 0);
        #pragma unroll
        for (int cc = 0; cc < 4; ++cc)
            acc[cc] = __builtin_amdgcn_mfma_f32_16x16x32_bf16(wA[cc].v, bx.v, acc[cc], 0, 0, 0);
        #pragma unroll
        for (int cc = 0; cc < 4; ++cc) {
            #pragma unroll
            for (int r = 0; r < 4; ++r)
                tot[cc][r] += fmaxf(acc[cc][r], 0.f);
        }
    }

    // butterfly allreduce over the 16 en-lanes (masks 1,2,4,8 stay inside qq group)
    #pragma unroll
    for (int m = 1; m < 16; m <<= 1) {
        #pragma unroll
        for (int cc = 0; cc < 4; ++cc) {
            #pragma unroll
            for (int r = 0; r < 4; ++r)
                tot[cc][r] += __shfl_xor(tot[cc][r], m);
        }
    }
    if (en == 0) {
        float* sp = Sacc + (size_t)node * 64 + qq * 16;
        #pragma unroll
        for (int cc = 0; cc < 4; ++cc)
            *(float4*)(sp + cc * 4) = make_float4(tot[cc][0], tot[cc][1], tot[cc][2], tot[cc][3]);
    }
}

// ---------------- fallback: per-edge atomic scatter (natural channel order) ----------------
__global__ __launch_bounds__(256) void k_edge_atom(
    const float* __restrict__ x, const int* __restrict__ ei, const float* __restrict__ ea,
    const float* __restrict__ W1a, const float* __restrict__ b1a,
    float* __restrict__ Sacc, int E)
{
    __shared__ float sWB[32 * 64];
    __shared__ float sWA[32 * 64];
    __shared__ float sb[64];
    for (int t = threadIdx.x; t < 32 * 64; t += 256) {
        sWB[t] = W1a[32 * 64 + t];
        sWA[t] = W1a[t];
    }
    if (threadIdx.x < 64) sb[threadIdx.x] = b1a[threadIdx.x];
    __syncthreads();
    int e = blockIdx.x * 256 + threadIdx.x;
    if (e >= E) return;
    int row = ei[e];
    int col = ei[NE + e];
    float h[64];
    #pragma unroll
    for (int j = 0; j < 64; ++j) h[j] = sb[j];
    const float4* xrow = (const float4*)(x + (size_t)col * 32);
    #pragma unroll
    for (int k4 = 0; k4 < 8; ++k4) {
        float4 v = xrow[k4];
        float vv[4] = {v.x, v.y, v.z, v.w};
        #pragma unroll
        for (int c = 0; c < 4; ++c) {
            float val = vv[c];
            const float4* wr = (const float4*)&sWA[(k4 * 4 + c) * 64];
            #pragma unroll
            for (int j4 = 0; j4 < 16; ++j4) {
                float4 w = wr[j4];
                h[j4 * 4 + 0] += val * w.x; h[j4 * 4 + 1] += val * w.y;
                h[j4 * 4 + 2] += val * w.z; h[j4 * 4 + 3] += val * w.w;
            }
        }
    }
    const float4* earow = (const float4*)(ea + (size_t)e * 32);
    #pragma unroll
    for (int k4 = 0; k4 < 8; ++k4) {
        float4 v = earow[k4];
        float vv[4] = {v.x, v.y, v.z, v.w};
        #pragma unroll
        for (int c = 0; c < 4; ++c) {
            float val = vv[c];
            const float4* wr = (const float4*)&sWB[(k4 * 4 + c) * 64];
            #pragma unroll
            for (int j4 = 0; j4 < 16; ++j4) {
                float4 w = wr[j4];
                h[j4 * 4 + 0] += val * w.x; h[j4 * 4 + 1] += val * w.y;
                h[j4 * 4 + 2] += val * w.z; h[j4 * 4 + 3] += val * w.w;
            }
        }
    }
    float* srow = Sacc + (size_t)row * 64;
    #pragma unroll
    for (int j = 0; j < 64; ++j) atomicAdd(&srow[j], fmaxf(h[j], 0.f));
}

// ---------------- node MLP: out = relu(x@W2a_top + (Sacc/d)@Wc + bc + b2a) @ W2b + b2b ----------------
__global__ __launch_bounds__(256) void k_node(
    const float* __restrict__ x, const float* __restrict__ Sacc, const int* __restrict__ deg,
    const float* __restrict__ Wc, const float* __restrict__ bc,
    const float* __restrict__ W2a, const float* __restrict__ b2a,
    const float* __restrict__ W2b, const float* __restrict__ b2b,
    float* __restrict__ out, int N)
{
    __shared__ float sWc[64 * 64];
    __shared__ float sW2ax[32 * 64];
    __shared__ float sW2b[64 * 32];
    __shared__ float sbc2[64];
    __shared__ float sb2[64];
    __shared__ float sb2b_[32];
    for (int t = threadIdx.x; t < 64 * 64; t += 256) sWc[t] = Wc[t];
    for (int t = threadIdx.x; t < 32 * 64; t += 256) sW2ax[t] = W2a[t];
    for (int t = threadIdx.x; t < 64 * 32; t += 256) sW2b[t] = W2b[t];
    if (threadIdx.x < 64) {
        sbc2[threadIdx.x] = bc[threadIdx.x] + b2a[threadIdx.x];
        sb2[threadIdx.x] = b2a[threadIdx.x];
    }
    if (threadIdx.x < 32) sb2b_[threadIdx.x] = b2b[threadIdx.x];
    __syncthreads();

    int i = blockIdx.x * 256 + threadIdx.x;
    if (i >= N) return;
    int d = deg[i];
    float inv = (d > 0) ? 1.f / (float)d : 0.f;

    float h2[64];
    #pragma unroll
    for (int j = 0; j < 64; ++j) h2[j] = (d > 0) ? sbc2[j] : sb2[j];

    const float4* sp = (const float4*)(Sacc + (size_t)i * 64);
    #pragma unroll 2
    for (int k4 = 0; k4 < 16; ++k4) {
        float4 v = sp[k4];
        float vv[4] = {v.x * inv, v.y * inv, v.z * inv, v.w * inv};
        #pragma unroll
        for (int c = 0; c < 4; ++c) {
            float val = vv[c];
            const float4* wr = (const float4*)&sWc[(k4 * 4 + c) * 64];
            #pragma unroll
            for (int j4 = 0; j4 < 16; ++j4) {
                float4 w = wr[j4];
                h2[j4 * 4 + 0] += val * w.x; h2[j4 * 4 + 1] += val * w.y;
                h2[j4 * 4 + 2] += val * w.z; h2[j4 * 4 + 3] += val * w.w;
            }
        }
    }
    const float4* xrow = (const float4*)(x + (size_t)i * 32);
    #pragma unroll 2
    for (int k4 = 0; k4 < 8; ++k4) {
        float4 v = xrow[k4];
        float vv[4] = {v.x, v.y, v.z, v.w};
        #pragma unroll
        for (int c = 0; c < 4; ++c) {
            float val = vv[c];
            const float4* wr = (const float4*)&sW2ax[(k4 * 4 + c) * 64];
            #pragma unroll
            for (int j4 = 0; j4 < 16; ++j4) {
                float4 w = wr[j4];
                h2[j4 * 4 + 0] += val * w.x; h2[j4 * 4 + 1] += val * w.y;
                h2[j4 * 4 + 2] += val * w.z; h2[j4 * 4 + 3] += val * w.w;
            }
        }
    }
    #pragma unroll
    for (int j = 0; j < 64; ++j) h2[j] = fmaxf(h2[j], 0.f);

    float o[32];
    #pragma unroll
    for (int j = 0; j < 32; ++j) o[j] = sb2b_[j];
    #pragma unroll
    for (int k = 0; k < 64; ++k) {
        float val = h2[k];
        const float4* wr = (const float4*)&sW2b[k * 32];
        #pragma unroll
        for (int j4 = 0; j4 < 8; ++j4) {
            float4 w = wr[j4];
            o[j4 * 4 + 0] += val * w.x; o[j4 * 4 + 1] += val * w.y;
            o[j4 * 4 + 2] += val * w.z; o[j4 * 4 + 3] += val * w.w;
        }
    }
    float4* orow = (float4*)(out + (size_t)i * 32);
    #pragma unroll
    for (int q = 0; q < 8; ++q)
        orow[q] = make_float4(o[q * 4], o[q * 4 + 1], o[q * 4 + 2], o[q * 4 + 3]);
}

extern "C" void kernel_launch(void* const* d_in, const int* in_sizes, int n_in,
                              void* d_out, int out_size, void* d_ws, size_t ws_size,
                              hipStream_t stream) {
    const float* x   = (const float*)d_in[0];
    const int*   ei  = (const int*)d_in[1];
    const float* ea  = (const float*)d_in[2];
    const float* W1a = (const float*)d_in[5];
    const float* b1a = (const float*)d_in[6];
    const float* W1b = (const float*)d_in[7];
    const float* b1b = (const float*)d_in[8];
    const float* W2a = (const float*)d_in[9];
    const float* b2a = (const float*)d_in[10];
    const float* W2b = (const float*)d_in[11];
    const float* b2b = (const float*)d_in[12];
    float* out = (float*)d_out;

    // workspace layout (~46 MB)
    char* p = (char*)d_ws;
    int* deg        = (int*)p;        p += (size_t)NN * 4;
    int* offs       = (int*)p;        p += (size_t)NN * 4;
    int* bsums      = (int*)p;        p += 2048;
    float* Wc       = (float*)p;      p += 4096 * 4;
    float* bc       = (float*)p;      p += 64 * 4;
    uint4* wpack    = (uint4*)p;      p += 512 * 16;
    size_t off_fb   = (size_t)(p - (char*)d_ws);     // fallback Sacc goes here
    int* rank       = (int*)p;        p += (size_t)NE * 4;
    int2* ecol      = (int2*)p;       p += (size_t)NE * 8;
    float* Sacc     = (float*)p;      p += (size_t)NN * 64 * 4;
    size_t need     = (size_t)(p - (char*)d_ws);

    dim3 blk(256);

    if (ws_size >= need) {
        hipMemsetAsync(deg, 0, (size_t)NN * 4, stream);
        hipLaunchKernelGGL(k_hist_rank, dim3((NE + 255) / 256), blk, 0, stream, ei, deg, rank, NE);
        hipLaunchKernelGGL(k_scan1, dim3(NB), blk, 0, stream, deg, offs, bsums, NN);
        hipLaunchKernelGGL(k_scan2, dim3(1), dim3(512), 0, stream, bsums, NB);
        hipLaunchKernelGGL(k_offs, dim3(NB), blk, 0, stream, offs, bsums, NN);
        hipLaunchKernelGGL(k_sorted, dim3((NE + 255) / 256), blk, 0, stream, ei, offs, rank, ecol, NE);
        hipLaunchKernelGGL(k_prep, dim3(16), blk, 0, stream, W1b, b1b, W2a, W1a, Wc, bc, wpack, 1);
        hipLaunchKernelGGL(k_edge_fused, dim3((NN + 3) / 4), blk, 0, stream,
                           ea, x, wpack, b1a, deg, offs, ecol, Sacc);
        hipLaunchKernelGGL(k_node, dim3(NB), blk, 0, stream,
                           x, Sacc, deg, Wc, bc, W2a, b2a, W2b, b2b, out, NN);
    } else {
        // fallback: fp32 atomic scatter (natural channel order), compact layout
        float* Sacc_fb = (float*)((char*)d_ws + off_fb);
        hipMemsetAsync(deg, 0, (size_t)NN * 4, stream);
        hipMemsetAsync(Sacc_fb, 0, (size_t)NN * 64 * 4, stream);
        hipLaunchKernelGGL(k_hist, dim3((NE + 255) / 256), blk, 0, stream, ei, deg, NE);
        hipLaunchKernelGGL(k_prep, dim3(16), blk, 0, stream, W1b, b1b, W2a, W1a, Wc, bc, wpack, 0);
        hipLaunchKernelGGL(k_edge_atom, dim3((NE + 255) / 256), blk, 0, stream,
                           x, ei, ea, W1a, b1a, Sacc_fb, NE);
        hipLaunchKernelGGL(k_node, dim3(NB), blk, 0, stream,
                           x, Sacc_fb, deg, Wc, bc, W2a, b2a, W2b, b2b, out, NN);
    }
}

// Round 10
// 311.510 us; speedup vs baseline: 1.0690x; 1.0062x over previous
//
#include <hip/hip_runtime.h>

#define NN 100000
#define NE 1600000
#define NB ((NN + 255) / 256)

typedef unsigned int uint32;
typedef unsigned short ushort16;
typedef float f32x4 __attribute__((ext_vector_type(4)));
typedef short bf16x8 __attribute__((ext_vector_type(8)));

__device__ __forceinline__ float bflo(uint32 u) { return __uint_as_float(u << 16); }
__device__ __forceinline__ float bfhi(uint32 u) { return __uint_as_float(u & 0xffff0000u); }
__device__ __forceinline__ uint32 bfbits(float v) { return (__float_as_uint(v) + 0x8000u) >> 16; }
__device__ __forceinline__ uint32 pack2(float a, float b) { return bfbits(a) | (bfbits(b) << 16); }

// channel permutation: sigma(c) swaps cc (bits 5:4) and qq (bits 3:2) fields
__device__ __forceinline__ int sigma_ch(int c) {
    return (((c >> 2) & 3) << 4) + (((c >> 4) & 3) << 2) + (c & 3);
}

// ---------------- CSR build ----------------
__global__ __launch_bounds__(256) void k_hist_rank(const int* __restrict__ ei, int* __restrict__ deg,
                                                   int* __restrict__ rank, int E) {
    int e = blockIdx.x * 256 + threadIdx.x;
    if (e < E) rank[e] = atomicAdd(&deg[ei[e]], 1);
}

__global__ __launch_bounds__(256) void k_hist(const int* __restrict__ ei, int* __restrict__ deg, int E) {
    int e = blockIdx.x * 256 + threadIdx.x;
    if (e < E) atomicAdd(&deg[ei[e]], 1);
}

__global__ __launch_bounds__(256) void k_scan1(const int* __restrict__ deg, int* __restrict__ offs,
                                               int* __restrict__ bsums, int n) {
    __shared__ int s[256];
    int tid = threadIdx.x;
    int i = blockIdx.x * 256 + tid;
    int v = (i < n) ? deg[i] : 0;
    int acc = v;
    s[tid] = acc;
    __syncthreads();
    #pragma unroll
    for (int off = 1; off < 256; off <<= 1) {
        int t = (tid >= off) ? s[tid - off] : 0;
        __syncthreads();
        acc += t;
        s[tid] = acc;
        __syncthreads();
    }
    if (i < n) offs[i] = acc - v;
    if (tid == 255) bsums[blockIdx.x] = acc;
}

__global__ __launch_bounds__(512) void k_scan2(int* __restrict__ bsums, int nb) {
    __shared__ int s[512];
    int tid = threadIdx.x;
    int v = (tid < nb) ? bsums[tid] : 0;
    int acc = v;
    s[tid] = acc;
    __syncthreads();
    #pragma unroll
    for (int off = 1; off < 512; off <<= 1) {
        int t = (tid >= off) ? s[tid - off] : 0;
        __syncthreads();
        acc += t;
        s[tid] = acc;
        __syncthreads();
    }
    bsums[tid] = acc - v;
}

__global__ __launch_bounds__(256) void k_offs(int* __restrict__ offs, const int* __restrict__ bsums, int n) {
    int i = blockIdx.x * 256 + threadIdx.x;
    if (i < n) offs[i] += bsums[i >> 8];
}

// ecol[offs[row] + rank[e]] = (e, col)
__global__ __launch_bounds__(256) void k_sorted(const int* __restrict__ ei, const int* __restrict__ offs,
                                                const int* __restrict__ rank, int2* __restrict__ ecol, int E) {
    int e = blockIdx.x * 256 + threadIdx.x;
    if (e >= E) return;
    int slot = offs[ei[e]] + rank[e];
    ecol[slot] = make_int2(e, ei[E + e]);
}

// ---------------- prep: Wc = W1b @ W2a[32:96] (rows sigma'd when perm), bc, wpack A-fragments ----------------
__global__ __launch_bounds__(256) void k_prep(const float* __restrict__ W1b, const float* __restrict__ b1b,
                                              const float* __restrict__ W2a, const float* __restrict__ W1a,
                                              float* __restrict__ Wc, float* __restrict__ bc,
                                              uint4* __restrict__ wpack, int perm) {
    int t = blockIdx.x * 256 + threadIdx.x;  // 0..4095
    int r = t >> 6, c = t & 63;
    float a = 0.f;
    for (int k = 0; k < 64; ++k) a += W1b[r * 64 + k] * W2a[(32 + k) * 64 + c];
    int rs = perm ? sigma_ch(r) : r;
    Wc[rs * 64 + c] = a;
    if (t < 64) {
        float bacc = 0.f;
        for (int k = 0; k < 64; ++k) bacc += b1b[k] * W2a[(32 + k) * 64 + t];
        bc[t] = bacc;
    }
    if (t < 512) {
        int table = t >> 8;
        int cc = (t >> 6) & 3;
        int lane = t & 63;
        int qq = lane >> 4, en = lane & 15;
        int ch = cc * 16 + en;
        uint32 w[4];
        #pragma unroll
        for (int j = 0; j < 4; ++j) {
            int k0 = qq * 8 + j * 2;
            int row0 = (table ? 0 : 32) + k0;
            w[j] = pack2(W1a[row0 * 64 + ch], W1a[(row0 + 1) * 64 + ch]);
        }
        wpack[t] = make_uint4(w[0], w[1], w[2], w[3]);
    }
}

// one 16-edge tile: pack B-frags, 8 MFMA, relu-accumulate
__device__ __forceinline__ void do_tile(
    const float4& a0, const float4& a1, const float4& x0, const float4& x1, bool ok,
    const bf16x8* wB, const bf16x8* wA, const f32x4* binit, f32x4* tot)
{
    union { uint4 u; bf16x8 v; } bea, bx;
    f32x4 acc[4];
    if (ok) {
        bea.u.x = pack2(a0.x, a0.y); bea.u.y = pack2(a0.z, a0.w);
        bea.u.z = pack2(a1.x, a1.y); bea.u.w = pack2(a1.z, a1.w);
        bx.u.x = pack2(x0.x, x0.y); bx.u.y = pack2(x0.z, x0.w);
        bx.u.z = pack2(x1.x, x1.y); bx.u.w = pack2(x1.z, x1.w);
        #pragma unroll
        for (int cc = 0; cc < 4; ++cc) acc[cc] = binit[cc];
    } else {
        bea.u = make_uint4(0, 0, 0, 0);
        bx.u = make_uint4(0, 0, 0, 0);
        #pragma unroll
        for (int cc = 0; cc < 4; ++cc) acc[cc] = (f32x4){0.f, 0.f, 0.f, 0.f};
    }
    #pragma unroll
    for (int cc = 0; cc < 4; ++cc)
        acc[cc] = __builtin_amdgcn_mfma_f32_16x16x32_bf16(wB[cc], bea.v, acc[cc], 0, 0, 0);
    #pragma unroll
    for (int cc = 0; cc < 4; ++cc)
        acc[cc] = __builtin_amdgcn_mfma_f32_16x16x32_bf16(wA[cc], bx.v, acc[cc], 0, 0, 0);
    #pragma unroll
    for (int cc = 0; cc < 4; ++cc) {
        #pragma unroll
        for (int r = 0; r < 4; ++r)
            tot[cc][r] += fmaxf(acc[cc][r], 0.f);
    }
}

// ---------------- fused edge MLP + segment sum: one wave per TWO nodes, dual chains in flight ----------------
__global__ __launch_bounds__(256) void k_edge_fused(
    const float* __restrict__ ea, const float* __restrict__ x,
    const uint4* __restrict__ wpack, const float* __restrict__ b1a,
    const int* __restrict__ deg, const int* __restrict__ offs, const int2* __restrict__ ecol,
    float* __restrict__ Sacc)
{
    int lane = threadIdx.x & 63;
    int wave = threadIdx.x >> 6;
    int en = lane & 15;
    int qq = lane >> 4;
    int wid = blockIdx.x * 4 + wave;
    int nA = wid * 2;
    if (nA >= NN) return;
    int nB = nA + 1;
    bool hasB = (nB < NN);

    union U { uint4 u; bf16x8 v; };
    U wBu[4], wAu[4];
    #pragma unroll
    for (int cc = 0; cc < 4; ++cc) {
        wBu[cc].u = wpack[cc * 64 + lane];
        wAu[cc].u = wpack[256 + cc * 64 + lane];
    }
    bf16x8 wB[4] = {wBu[0].v, wBu[1].v, wBu[2].v, wBu[3].v};
    bf16x8 wA[4] = {wAu[0].v, wAu[1].v, wAu[2].v, wAu[3].v};
    f32x4 binit[4];
    #pragma unroll
    for (int cc = 0; cc < 4; ++cc) {
        float4 b = *(const float4*)(b1a + cc * 16 + qq * 4);
        binit[cc] = (f32x4){b.x, b.y, b.z, b.w};
    }

    int dA = deg[nA], stA = offs[nA];
    int dB = hasB ? deg[nB] : 0;
    int stB = hasB ? offs[nB] : stA;

    // ---- issue BOTH nodes' tile-0 chains before any compute ----
    int slA = stA + (en < dA ? en : (dA > 0 ? dA - 1 : 0));
    if (slA > NE - 1) slA = NE - 1;
    int slB = stB + (en < dB ? en : (dB > 0 ? dB - 1 : 0));
    if (slB > NE - 1) slB = NE - 1;
    int2 ecA = ecol[slA];
    int2 ecB = ecol[slB];

    const float* arA = ea + (size_t)ecA.x * 32 + qq * 8;
    float4 aA0 = *(const float4*)arA;
    float4 aA1 = *(const float4*)(arA + 4);
    const float* xrA = x + (size_t)ecA.y * 32 + qq * 8;
    float4 xA0 = *(const float4*)xrA;
    float4 xA1 = *(const float4*)(xrA + 4);

    const float* arB = ea + (size_t)ecB.x * 32 + qq * 8;
    float4 aB0 = *(const float4*)arB;
    float4 aB1 = *(const float4*)(arB + 4);
    const float* xrB = x + (size_t)ecB.y * 32 + qq * 8;
    float4 xB0 = *(const float4*)xrB;
    float4 xB1 = *(const float4*)(xrB + 4);

    f32x4 totA[4], totB[4];
    #pragma unroll
    for (int cc = 0; cc < 4; ++cc) {
        totA[cc] = (f32x4){0.f, 0.f, 0.f, 0.f};
        totB[cc] = (f32x4){0.f, 0.f, 0.f, 0.f};
    }

    do_tile(aA0, aA1, xA0, xA1, en < dA, wB, wA, binit, totA);
    do_tile(aB0, aB1, xB0, xB1, en < dB, wB, wA, binit, totB);

    // rare serial tails (d > 16)
    #pragma unroll 1
    for (int t0 = 16; t0 < dA; t0 += 16) {
        int sidx = t0 + en;
        bool ok = sidx < dA;
        int sl = stA + (ok ? sidx : dA - 1);
        int2 ec = ecol[sl];
        const float* ar = ea + (size_t)ec.x * 32 + qq * 8;
        float4 a0 = *(const float4*)ar;
        float4 a1 = *(const float4*)(ar + 4);
        const float* xr = x + (size_t)ec.y * 32 + qq * 8;
        float4 x0 = *(const float4*)xr;
        float4 x1 = *(const float4*)(xr + 4);
        do_tile(a0, a1, x0, x1, ok, wB, wA, binit, totA);
    }
    #pragma unroll 1
    for (int t0 = 16; t0 < dB; t0 += 16) {
        int sidx = t0 + en;
        bool ok = sidx < dB;
        int sl = stB + (ok ? sidx : dB - 1);
        int2 ec = ecol[sl];
        const float* ar = ea + (size_t)ec.x * 32 + qq * 8;
        float4 a0 = *(const float4*)ar;
        float4 a1 = *(const float4*)(ar + 4);
        const float* xr = x + (size_t)ec.y * 32 + qq * 8;
        float4 x0 = *(const float4*)xr;
        float4 x1 = *(const float4*)(xr + 4);
        do_tile(a0, a1, x0, x1, ok, wB, wA, binit, totB);
    }

    // dual butterfly allreduce over en-lanes (independent chains interleave)
    #pragma unroll
    for (int m = 1; m < 16; m <<= 1) {
        #pragma unroll
        for (int cc = 0; cc < 4; ++cc) {
            #pragma unroll
            for (int r = 0; r < 4; ++r) {
                totA[cc][r] += __shfl_xor(totA[cc][r], m);
                totB[cc][r] += __shfl_xor(totB[cc][r], m);
            }
        }
    }
    if (en == 0) {
        float* spA = Sacc + (size_t)nA * 64 + qq * 16;
        #pragma unroll
        for (int cc = 0; cc < 4; ++cc)
            *(float4*)(spA + cc * 4) = make_float4(totA[cc][0], totA[cc][1], totA[cc][2], totA[cc][3]);
        if (hasB) {
            float* spB = Sacc + (size_t)nB * 64 + qq * 16;
            #pragma unroll
            for (int cc = 0; cc < 4; ++cc)
                *(float4*)(spB + cc * 4) = make_float4(totB[cc][0], totB[cc][1], totB[cc][2], totB[cc][3]);
        }
    }
}

// ---------------- fallback: per-edge atomic scatter (natural channel order) ----------------
__global__ __launch_bounds__(256) void k_edge_atom(
    const float* __restrict__ x, const int* __restrict__ ei, const float* __restrict__ ea,
    const float* __restrict__ W1a, const float* __restrict__ b1a,
    float* __restrict__ Sacc, int E)
{
    __shared__ float sWB[32 * 64];
    __shared__ float sWA[32 * 64];
    __shared__ float sb[64];
    for (int t = threadIdx.x; t < 32 * 64; t += 256) {
        sWB[t] = W1a[32 * 64 + t];
        sWA[t] = W1a[t];
    }
    if (threadIdx.x < 64) sb[threadIdx.x] = b1a[threadIdx.x];
    __syncthreads();
    int e = blockIdx.x * 256 + threadIdx.x;
    if (e >= E) return;
    int row = ei[e];
    int col = ei[NE + e];
    float h[64];
    #pragma unroll
    for (int j = 0; j < 64; ++j) h[j] = sb[j];
    const float4* xrow = (const float4*)(x + (size_t)col * 32);
    #pragma unroll
    for (int k4 = 0; k4 < 8; ++k4) {
        float4 v = xrow[k4];
        float vv[4] = {v.x, v.y, v.z, v.w};
        #pragma unroll
        for (int c = 0; c < 4; ++c) {
            float val = vv[c];
            const float4* wr = (const float4*)&sWA[(k4 * 4 + c) * 64];
            #pragma unroll
            for (int j4 = 0; j4 < 16; ++j4) {
                float4 w = wr[j4];
                h[j4 * 4 + 0] += val * w.x; h[j4 * 4 + 1] += val * w.y;
                h[j4 * 4 + 2] += val * w.z; h[j4 * 4 + 3] += val * w.w;
            }
        }
    }
    const float4* earow = (const float4*)(ea + (size_t)e * 32);
    #pragma unroll
    for (int k4 = 0; k4 < 8; ++k4) {
        float4 v = earow[k4];
        float vv[4] = {v.x, v.y, v.z, v.w};
        #pragma unroll
        for (int c = 0; c < 4; ++c) {
            float val = vv[c];
            const float4* wr = (const float4*)&sWB[(k4 * 4 + c) * 64];
            #pragma unroll
            for (int j4 = 0; j4 < 16; ++j4) {
                float4 w = wr[j4];
                h[j4 * 4 + 0] += val * w.x; h[j4 * 4 + 1] += val * w.y;
                h[j4 * 4 + 2] += val * w.z; h[j4 * 4 + 3] += val * w.w;
            }
        }
    }
    float* srow = Sacc + (size_t)row * 64;
    #pragma unroll
    for (int j = 0; j < 64; ++j) atomicAdd(&srow[j], fmaxf(h[j], 0.f));
}

// ---------------- node MLP: out = relu(x@W2a_top + (Sacc/d)@Wc + bc + b2a) @ W2b + b2b ----------------
__global__ __launch_bounds__(256) void k_node(
    const float* __restrict__ x, const float* __restrict__ Sacc, const int* __restrict__ deg,
    const float* __restrict__ Wc, const float* __restrict__ bc,
    const float* __restrict__ W2a, const float* __restrict__ b2a,
    const float* __restrict__ W2b, const float* __restrict__ b2b,
    float* __restrict__ out, int N)
{
    __shared__ float sWc[64 * 64];
    __shared__ float sW2ax[32 * 64];
    __shared__ float sW2b[64 * 32];
    __shared__ float sbc2[64];
    __shared__ float sb2[64];
    __shared__ float sb2b_[32];
    for (int t = threadIdx.x; t < 64 * 64; t += 256) sWc[t] = Wc[t];
    for (int t = threadIdx.x; t < 32 * 64; t += 256) sW2ax[t] = W2a[t];
    for (int t = threadIdx.x; t < 64 * 32; t += 256) sW2b[t] = W2b[t];
    if (threadIdx.x < 64) {
        sbc2[threadIdx.x] = bc[threadIdx.x] + b2a[threadIdx.x];
        sb2[threadIdx.x] = b2a[threadIdx.x];
    }
    if (threadIdx.x < 32) sb2b_[threadIdx.x] = b2b[threadIdx.x];
    __syncthreads();

    int i = blockIdx.x * 256 + threadIdx.x;
    if (i >= N) return;
    int d = deg[i];
    float inv = (d > 0) ? 1.f / (float)d : 0.f;

    float h2[64];
    #pragma unroll
    for (int j = 0; j < 64; ++j) h2[j] = (d > 0) ? sbc2[j] : sb2[j];

    const float4* sp = (const float4*)(Sacc + (size_t)i * 64);
    #pragma unroll 2
    for (int k4 = 0; k4 < 16; ++k4) {
        float4 v = sp[k4];
        float vv[4] = {v.x * inv, v.y * inv, v.z * inv, v.w * inv};
        #pragma unroll
        for (int c = 0; c < 4; ++c) {
            float val = vv[c];
            const float4* wr = (const float4*)&sWc[(k4 * 4 + c) * 64];
            #pragma unroll
            for (int j4 = 0; j4 < 16; ++j4) {
                float4 w = wr[j4];
                h2[j4 * 4 + 0] += val * w.x; h2[j4 * 4 + 1] += val * w.y;
                h2[j4 * 4 + 2] += val * w.z; h2[j4 * 4 + 3] += val * w.w;
            }
        }
    }
    const float4* xrow = (const float4*)(x + (size_t)i * 32);
    #pragma unroll 2
    for (int k4 = 0; k4 < 8; ++k4) {
        float4 v = xrow[k4];
        float vv[4] = {v.x, v.y, v.z, v.w};
        #pragma unroll
        for (int c = 0; c < 4; ++c) {
            float val = vv[c];
            const float4* wr = (const float4*)&sW2ax[(k4 * 4 + c) * 64];
            #pragma unroll
            for (int j4 = 0; j4 < 16; ++j4) {
                float4 w = wr[j4];
                h2[j4 * 4 + 0] += val * w.x; h2[j4 * 4 + 1] += val * w.y;
                h2[j4 * 4 + 2] += val * w.z; h2[j4 * 4 + 3] += val * w.w;
            }
        }
    }
    #pragma unroll
    for (int j = 0; j < 64; ++j) h2[j] = fmaxf(h2[j], 0.f);

    float o[32];
    #pragma unroll
    for (int j = 0; j < 32; ++j) o[j] = sb2b_[j];
    #pragma unroll
    for (int k = 0; k < 64; ++k) {
        float val = h2[k];
        const float4* wr = (const float4*)&sW2b[k * 32];
        #pragma unroll
        for (int j4 = 0; j4 < 8; ++j4) {
            float4 w = wr[j4];
            o[j4 * 4 + 0] += val * w.x; o[j4 * 4 + 1] += val * w.y;
            o[j4 * 4 + 2] += val * w.z; o[j4 * 4 + 3] += val * w.w;
        }
    }
    float4* orow = (float4*)(out + (size_t)i * 32);
    #pragma unroll
    for (int q = 0; q < 8; ++q)
        orow[q] = make_float4(o[q * 4], o[q * 4 + 1], o[q * 4 + 2], o[q * 4 + 3]);
}

extern "C" void kernel_launch(void* const* d_in, const int* in_sizes, int n_in,
                              void* d_out, int out_size, void* d_ws, size_t ws_size,
                              hipStream_t stream) {
    const float* x   = (const float*)d_in[0];
    const int*   ei  = (const int*)d_in[1];
    const float* ea  = (const float*)d_in[2];
    const float* W1a = (const float*)d_in[5];
    const float* b1a = (const float*)d_in[6];
    const float* W1b = (const float*)d_in[7];
    const float* b1b = (const float*)d_in[8];
    const float* W2a = (const float*)d_in[9];
    const float* b2a = (const float*)d_in[10];
    const float* W2b = (const float*)d_in[11];
    const float* b2b = (const float*)d_in[12];
    float* out = (float*)d_out;

    // workspace layout (~46 MB)
    char* p = (char*)d_ws;
    int* deg        = (int*)p;        p += (size_t)NN * 4;
    int* offs       = (int*)p;        p += (size_t)NN * 4;
    int* bsums      = (int*)p;        p += 2048;
    float* Wc       = (float*)p;      p += 4096 * 4;
    float* bc       = (float*)p;      p += 64 * 4;
    uint4* wpack    = (uint4*)p;      p += 512 * 16;
    size_t off_fb   = (size_t)(p - (char*)d_ws);     // fallback Sacc goes here
    int* rank       = (int*)p;        p += (size_t)NE * 4;
    int2* ecol      = (int2*)p;       p += (size_t)NE * 8;
    float* Sacc     = (float*)p;      p += (size_t)NN * 64 * 4;
    size_t need     = (size_t)(p - (char*)d_ws);

    dim3 blk(256);

    if (ws_size >= need) {
        hipMemsetAsync(deg, 0, (size_t)NN * 4, stream);
        hipLaunchKernelGGL(k_hist_rank, dim3((NE + 255) / 256), blk, 0, stream, ei, deg, rank, NE);
        hipLaunchKernelGGL(k_scan1, dim3(NB), blk, 0, stream, deg, offs, bsums, NN);
        hipLaunchKernelGGL(k_scan2, dim3(1), dim3(512), 0, stream, bsums, NB);
        hipLaunchKernelGGL(k_offs, dim3(NB), blk, 0, stream, offs, bsums, NN);
        hipLaunchKernelGGL(k_sorted, dim3((NE + 255) / 256), blk, 0, stream, ei, offs, rank, ecol, NE);
        hipLaunchKernelGGL(k_prep, dim3(16), blk, 0, stream, W1b, b1b, W2a, W1a, Wc, bc, wpack, 1);
        // 2 nodes per wave, 4 waves per block
        int nwaves = (NN + 1) / 2;
        hipLaunchKernelGGL(k_edge_fused, dim3((nwaves + 3) / 4), blk, 0, stream,
                           ea, x, wpack, b1a, deg, offs, ecol, Sacc);
        hipLaunchKernelGGL(k_node, dim3(NB), blk, 0, stream,
                           x, Sacc, deg, Wc, bc, W2a, b2a, W2b, b2b, out, NN);
    } else {
        // fallback: fp32 atomic scatter (natural channel order), compact layout
        float* Sacc_fb = (float*)((char*)d_ws + off_fb);
        hipMemsetAsync(deg, 0, (size_t)NN * 4, stream);
        hipMemsetAsync(Sacc_fb, 0, (size_t)NN * 64 * 4, stream);
        hipLaunchKernelGGL(k_hist, dim3((NE + 255) / 256), blk, 0, stream, ei, deg, NE);
        hipLaunchKernelGGL(k_prep, dim3(16), blk, 0, stream, W1b, b1b, W2a, W1a, Wc, bc, wpack, 0);
        hipLaunchKernelGGL(k_edge_atom, dim3((NE + 255) / 256), blk, 0, stream,
                           x, ei, ea, W1a, b1a, Sacc_fb, NE);
        hipLaunchKernelGGL(k_node, dim3(NB), blk, 0, stream,
                           x, Sacc_fb, deg, Wc, bc, W2a, b2a, W2b, b2b, out, NN);
    }
}